// Round 1
// baseline (164.692 us; speedup 1.0000x reference)
//
#include <hip/hip_runtime.h>
#include <math.h>

#define Bn 32
#define Fn 1024
#define Dn 256
#define Hn 4
#define En 64
#define FFn 4096
#define LN_EPS 1e-5f
#define FC1 16
#define FCH1 (Fn/FC1)   // 64
#define JC2 32
#define JCH2 (FFn/JC2)  // 128

__device__ __forceinline__ float wsum(float v) {
#pragma unroll
    for (int off = 32; off; off >>= 1) v += __shfl_xor(v, off, 64);
    return v;
}
__device__ __forceinline__ float wmax(float v) {
#pragma unroll
    for (int off = 32; off; off >>= 1) v = fmaxf(v, __shfl_xor(v, off, 64));
    return v;
}

// wvo[h,d] = sum_e Wv[h,d,e] * Wo[h*E+e]
__global__ void k_wvo(const float* __restrict__ Wv, const float* __restrict__ Wo,
                      float* __restrict__ wvo) {
    int idx = blockIdx.x * 256 + threadIdx.x;   // h*Dn + d, total 1024
    int h = idx >> 8, d = idx & 255;
    const float* wv = Wv + (h * Dn + d) * En;
    const float* wo = Wo + h * En;
    float s = 0.f;
#pragma unroll 8
    for (int e = 0; e < En; e++) s = fmaf(wv[e], wo[e], s);
    wvo[idx] = s;
}

// h = LN(x, g1, b1), row-major (B,F)
__global__ void k_ln1(const float* __restrict__ x, const float* __restrict__ g,
                      const float* __restrict__ bt, float* __restrict__ out) {
    int b = blockIdx.x;
    int tid = threadIdx.x;
    const float* xr = x + b * Fn;
    float v[4];
    float s = 0.f;
#pragma unroll
    for (int i = 0; i < 4; i++) { v[i] = xr[tid + 256 * i]; s += v[i]; }
    __shared__ float red[4];
    s = wsum(s);
    int wid = tid >> 6, lane = tid & 63;
    if (lane == 0) red[wid] = s;
    __syncthreads();
    float mu = (red[0] + red[1] + red[2] + red[3]) * (1.f / Fn);
    float vs = 0.f;
#pragma unroll
    for (int i = 0; i < 4; i++) { float d = v[i] - mu; vs = fmaf(d, d, vs); }
    vs = wsum(vs);
    __syncthreads();
    if (lane == 0) red[wid] = vs;
    __syncthreads();
    float var = (red[0] + red[1] + red[2] + red[3]) * (1.f / Fn);
    float rs = rsqrtf(var + LN_EPS);
#pragma unroll
    for (int i = 0; i < 4; i++) {
        int f = tid + 256 * i;
        out[b * Fn + f] = (v[i] - mu) * rs * g[f] + bt[f];
    }
}

// Eq[h][f][e] = sum_d emb[f,d] Wq[h,d,e];  EkT[h][e][f] likewise for Wk (transposed store)
__global__ void k_proj(const float* __restrict__ emb,
                       const float* __restrict__ Wq, const float* __restrict__ Wk,
                       float* __restrict__ Eq, float* __restrict__ EkT) {
    int h = blockIdx.y;
    int f = blockIdx.x * 4 + (threadIdx.x >> 6);
    int e = threadIdx.x & 63;
    const float* er = emb + f * Dn;
    const float* wq = Wq + h * Dn * En + e;
    const float* wk = Wk + h * Dn * En + e;
    float aq = 0.f, ak = 0.f;
#pragma unroll 4
    for (int d = 0; d < Dn; d++) {
        float ev = er[d];
        aq = fmaf(ev, wq[d * En], aq);
        ak = fmaf(ev, wk[d * En], ak);
    }
    Eq[(h * Fn + f) * En + e] = aq;
    EkT[(h * En + e) * Fn + f] = ak;
}

// Evo[h][g] = sum_d emb[g,d] * wvo[h,d]; one wave per (h,g)
__global__ void k_evo(const float* __restrict__ emb, const float* __restrict__ wvo,
                      float* __restrict__ Evo) {
    int gidx = blockIdx.x * 4 + (threadIdx.x >> 6); // h*Fn+g
    int h = gidx >> 10, g = gidx & 1023;
    int lane = threadIdx.x & 63;
    const float* er = emb + g * Dn + lane;
    const float* wv = wvo + h * Dn + lane;
    float s = 0.f;
#pragma unroll
    for (int d = 0; d < Dn; d += 64) s = fmaf(er[d], wv[d], s);
    s = wsum(s);
    if (lane == 0) Evo[gidx] = s;
}

// S0[h][f][g] = (1/8) sum_e Eq[h][f][e] * EkT[h][e][g]
__global__ void k_s0(const float* __restrict__ Eq, const float* __restrict__ EkT,
                     float* __restrict__ S0) {
    int h = blockIdx.z;
    int f0 = blockIdx.y * 16;
    int g = blockIdx.x * 256 + threadIdx.x;
    const float* ekt = EkT + h * En * Fn + g;
    const float* eq = Eq + (h * Fn + f0) * En;
    float acc[16] = {};
    for (int e = 0; e < En; e++) {
        float kv = ekt[e * Fn];
#pragma unroll
        for (int ff = 0; ff < 16; ff++)
            acc[ff] = fmaf(eq[ff * En + e], kv, acc[ff]);
    }
    float* so = S0 + (h * Fn + f0) * Fn + g;
#pragma unroll
    for (int ff = 0; ff < 16; ff++) so[ff * Fn] = acc[ff] * 0.125f;
}

// per (h,f) row: loop b, softmax over g of hf*hg*S0, weighted sum of hg*Evo
__global__ void k_attn(const float* __restrict__ S0, const float* __restrict__ hbuf,
                       const float* __restrict__ Evo, float* __restrict__ part) {
    __shared__ float hg[Fn];
    int h = blockIdx.y;
    int wid = threadIdx.x >> 6, lane = threadIdx.x & 63;
    int f = blockIdx.x * 4 + wid;
    const float4* s0row = (const float4*)(S0 + (h * Fn + f) * Fn);
    const float4* evo4 = (const float4*)(Evo + h * Fn);
    float4 s0r[4], evr[4];
#pragma unroll
    for (int k = 0; k < 4; k++) {
        s0r[k] = s0row[k * 64 + lane];
        evr[k] = evo4[k * 64 + lane];
    }
    for (int b = 0; b < Bn; b++) {
        const float4* hr4 = (const float4*)(hbuf + b * Fn);
        ((float4*)hg)[threadIdx.x] = hr4[threadIdx.x];
        __syncthreads();
        float hf = hg[f];
        float4 hgv[4];
        float t[4][4];
        float m = -1e30f;
#pragma unroll
        for (int k = 0; k < 4; k++) {
            hgv[k] = ((float4*)hg)[k * 64 + lane];
            t[k][0] = hf * hgv[k].x * s0r[k].x;
            t[k][1] = hf * hgv[k].y * s0r[k].y;
            t[k][2] = hf * hgv[k].z * s0r[k].z;
            t[k][3] = hf * hgv[k].w * s0r[k].w;
            m = fmaxf(m, fmaxf(fmaxf(t[k][0], t[k][1]), fmaxf(t[k][2], t[k][3])));
        }
        m = wmax(m);
        float s = 0.f, o = 0.f;
#pragma unroll
        for (int k = 0; k < 4; k++) {
            float p0 = __expf(t[k][0] - m);
            float p1 = __expf(t[k][1] - m);
            float p2 = __expf(t[k][2] - m);
            float p3 = __expf(t[k][3] - m);
            s += p0 + p1 + p2 + p3;
            o = fmaf(p0, hgv[k].x * evr[k].x, o);
            o = fmaf(p1, hgv[k].y * evr[k].y, o);
            o = fmaf(p2, hgv[k].z * evr[k].z, o);
            o = fmaf(p3, hgv[k].w * evr[k].w, o);
        }
        s = wsum(s);
        o = wsum(o);
        if (lane == 0) part[(h * Bn + b) * Fn + f] = o / s;
        __syncthreads();
    }
}

// xmid = x + bo + sum_h part; LN2 -> h2T[f*B+b]
__global__ void k_mid(const float* __restrict__ x, const float* __restrict__ part,
                      const float* __restrict__ bo, const float* __restrict__ g2,
                      const float* __restrict__ b2, float* __restrict__ xmid,
                      float* __restrict__ h2T) {
    int b = blockIdx.x;
    int tid = threadIdx.x;
    float bov = bo[0];
    float v[4];
    float s = 0.f;
#pragma unroll
    for (int i = 0; i < 4; i++) {
        int f = tid + 256 * i;
        float xv = x[b * Fn + f] + bov;
#pragma unroll
        for (int h = 0; h < Hn; h++) xv += part[(h * Bn + b) * Fn + f];
        v[i] = xv;
        s += xv;
        xmid[b * Fn + f] = xv;
    }
    __shared__ float red[4];
    s = wsum(s);
    int wid = tid >> 6, lane = tid & 63;
    if (lane == 0) red[wid] = s;
    __syncthreads();
    float mu = (red[0] + red[1] + red[2] + red[3]) * (1.f / Fn);
    float vs = 0.f;
#pragma unroll
    for (int i = 0; i < 4; i++) { float d = v[i] - mu; vs = fmaf(d, d, vs); }
    vs = wsum(vs);
    __syncthreads();
    if (lane == 0) red[wid] = vs;
    __syncthreads();
    float var = (red[0] + red[1] + red[2] + red[3]) * (1.f / Fn);
    float rs = rsqrtf(var + LN_EPS);
#pragma unroll
    for (int i = 0; i < 4; i++) {
        int f = tid + 256 * i;
        h2T[f * Bn + b] = (v[i] - mu) * rs * g2[f] + b2[f];
    }
}

// C1p[fc][b][j] = sum_{f in chunk} h2T[f][b] * W1[f][j]
__global__ void k_ffn1(const float* __restrict__ h2T, const float* __restrict__ W1,
                       float* __restrict__ C1p) {
    int j = blockIdx.x * 256 + threadIdx.x;
    int fc = blockIdx.y;
    const float* w = W1 + (fc * FCH1) * FFn + j;
    const float* ht = h2T + (fc * FCH1) * Bn;
    float acc[Bn] = {};
    for (int f = 0; f < FCH1; f++) {
        float wv = w[f * FFn];
#pragma unroll
        for (int b = 0; b < Bn; b++) acc[b] = fmaf(ht[f * Bn + b], wv, acc[b]);
    }
    float* cp = C1p + (fc * Bn) * FFn + j;
#pragma unroll
    for (int b = 0; b < Bn; b++) cp[b * FFn] = acc[b];
}

// U^T[j][b] = gelu(bf1[j] + sum_fc C1p[fc][b][j])
__global__ void k_gelu(const float* __restrict__ C1p, const float* __restrict__ bf1,
                       float* __restrict__ UT) {
    int idx = blockIdx.x * 256 + threadIdx.x;  // b*FFn + j
    int b = idx >> 12, j = idx & 4095;
    float s = bf1[j];
#pragma unroll
    for (int fc = 0; fc < FC1; fc++) s += C1p[(fc * Bn + b) * FFn + j];
    float u = 0.5f * s * (1.f + erff(s * 0.70710678118654752f));
    UT[j * Bn + b] = u;
}

// C2p[jc][b][i] = sum_{j in chunk} UT[j][b] * W2[j][i]
__global__ void k_ffn2(const float* __restrict__ UT, const float* __restrict__ W2,
                       float* __restrict__ C2p) {
    int i = blockIdx.x * 256 + threadIdx.x;
    int jc = blockIdx.y;
    const float* w = W2 + (jc * JCH2) * Fn + i;
    const float* ut = UT + (jc * JCH2) * Bn;
    float acc[Bn] = {};
    for (int j = 0; j < JCH2; j++) {
        float wv = w[j * Fn];
#pragma unroll
        for (int b = 0; b < Bn; b++) acc[b] = fmaf(ut[j * Bn + b], wv, acc[b]);
    }
    float* cp = C2p + (jc * Bn) * Fn + i;
#pragma unroll
    for (int b = 0; b < Bn; b++) cp[b * Fn] = acc[b];
}

// out = xmid + bf2 + sum_jc C2p
__global__ void k_final(const float* __restrict__ xmid, const float* __restrict__ C2p,
                        const float* __restrict__ bf2, float* __restrict__ out) {
    int idx = blockIdx.x * 256 + threadIdx.x;  // b*Fn + f
    int b = idx >> 10, f = idx & 1023;
    float s = xmid[idx] + bf2[f];
#pragma unroll
    for (int jc = 0; jc < JC2; jc++) s += C2p[(jc * Bn + b) * Fn + f];
    out[idx] = s;
}

extern "C" void kernel_launch(void* const* d_in, const int* in_sizes, int n_in,
                              void* d_out, int out_size, void* d_ws, size_t ws_size,
                              hipStream_t stream) {
    (void)in_sizes; (void)n_in; (void)out_size; (void)ws_size;
    const float* x   = (const float*)d_in[0];
    const float* emb = (const float*)d_in[1];
    const float* Wq  = (const float*)d_in[2];
    const float* Wk  = (const float*)d_in[3];
    const float* Wv  = (const float*)d_in[4];
    const float* Wo  = (const float*)d_in[5];
    const float* bo  = (const float*)d_in[6];
    const float* g1  = (const float*)d_in[7];
    const float* b1  = (const float*)d_in[8];
    const float* g2  = (const float*)d_in[9];
    const float* b2  = (const float*)d_in[10];
    const float* W1  = (const float*)d_in[11];
    const float* bf1 = (const float*)d_in[12];
    const float* W2  = (const float*)d_in[13];
    const float* bf2 = (const float*)d_in[14];
    float* out = (float*)d_out;

    float* ws = (float*)d_ws;
    size_t o = 0;
    float* S0   = ws + o; o += (size_t)Hn * Fn * Fn;   // 4194304
    float* Eq   = ws + o; o += (size_t)Hn * Fn * En;   // 262144
    float* EkT  = ws + o; o += (size_t)Hn * En * Fn;   // 262144
    float* Evo  = ws + o; o += (size_t)Hn * Fn;        // 4096
    float* wvo  = ws + o; o += (size_t)Hn * Dn;        // 1024
    float* hbuf = ws + o; o += (size_t)Bn * Fn;        // 32768
    float* part = ws + o; o += (size_t)Hn * Bn * Fn;   // 131072
    float* xmid = ws + o; o += (size_t)Bn * Fn;        // 32768
    float* h2T  = ws + o; o += (size_t)Fn * Bn;        // 32768
    float* C1p  = ws + o; o += (size_t)FC1 * Bn * FFn; // 2097152
    float* UT   = ws + o; o += (size_t)FFn * Bn;       // 131072
    float* C2p  = ws + o; o += (size_t)JC2 * Bn * Fn;  // 1048576

    k_wvo<<<dim3(Hn * Dn / 256), 256, 0, stream>>>(Wv, Wo, wvo);
    k_ln1<<<dim3(Bn), 256, 0, stream>>>(x, g1, b1, hbuf);
    k_proj<<<dim3(Fn / 4, Hn), 256, 0, stream>>>(emb, Wq, Wk, Eq, EkT);
    k_evo<<<dim3(Hn * Fn / 4), 256, 0, stream>>>(emb, wvo, Evo);
    k_s0<<<dim3(Fn / 256, Fn / 16, Hn), 256, 0, stream>>>(Eq, EkT, S0);
    k_attn<<<dim3(Fn / 4, Hn), 256, 0, stream>>>(S0, hbuf, Evo, part);
    k_mid<<<dim3(Bn), 256, 0, stream>>>(x, part, bo, g2, b2, xmid, h2T);
    k_ffn1<<<dim3(FFn / 256, FC1), 256, 0, stream>>>(h2T, W1, C1p);
    k_gelu<<<dim3(Bn * FFn / 256), 256, 0, stream>>>(C1p, bf1, UT);
    k_ffn2<<<dim3(Fn / 256, JC2), 256, 0, stream>>>(UT, W2, C2p);
    k_final<<<dim3(Bn * Fn / 256), 256, 0, stream>>>(xmid, C2p, bf2, out);
}

// Round 2
// 156.186 us; speedup vs baseline: 1.0545x; 1.0545x over previous
//
#include <hip/hip_runtime.h>
#include <math.h>

#define Bn 32
#define Fn 1024
#define Dn 256
#define Hn 4
#define En 64
#define FFn 4096
#define LN_EPS 1e-5f
#define FC1 16
#define FCH1 (Fn/FC1)   // 64
#define JC2 32
#define JCH2 (FFn/JC2)  // 128
#define BT 8            // batch tile in k_attn

__device__ __forceinline__ float wsum(float v) {
#pragma unroll
    for (int off = 32; off; off >>= 1) v += __shfl_xor(v, off, 64);
    return v;
}

// wvo[h,d] = sum_e Wv[h,d,e] * Wo[h*E+e]
__global__ void k_wvo(const float* __restrict__ Wv, const float* __restrict__ Wo,
                      float* __restrict__ wvo) {
    int idx = blockIdx.x * 256 + threadIdx.x;   // h*Dn + d, total 1024
    int h = idx >> 8, d = idx & 255;
    const float* wv = Wv + (h * Dn + d) * En;
    const float* wo = Wo + h * En;
    float s = 0.f;
#pragma unroll 8
    for (int e = 0; e < En; e++) s = fmaf(wv[e], wo[e], s);
    wvo[idx] = s;
}

// h = LN(x, g1, b1), row-major (B,F)
__global__ void k_ln1(const float* __restrict__ x, const float* __restrict__ g,
                      const float* __restrict__ bt, float* __restrict__ out) {
    int b = blockIdx.x;
    int tid = threadIdx.x;
    const float* xr = x + b * Fn;
    float v[4];
    float s = 0.f;
#pragma unroll
    for (int i = 0; i < 4; i++) { v[i] = xr[tid + 256 * i]; s += v[i]; }
    __shared__ float red[4];
    s = wsum(s);
    int wid = tid >> 6, lane = tid & 63;
    if (lane == 0) red[wid] = s;
    __syncthreads();
    float mu = (red[0] + red[1] + red[2] + red[3]) * (1.f / Fn);
    float vs = 0.f;
#pragma unroll
    for (int i = 0; i < 4; i++) { float d = v[i] - mu; vs = fmaf(d, d, vs); }
    vs = wsum(vs);
    __syncthreads();
    if (lane == 0) red[wid] = vs;
    __syncthreads();
    float var = (red[0] + red[1] + red[2] + red[3]) * (1.f / Fn);
    float rs = rsqrtf(var + LN_EPS);
#pragma unroll
    for (int i = 0; i < 4; i++) {
        int f = tid + 256 * i;
        out[b * Fn + f] = (v[i] - mu) * rs * g[f] + bt[f];
    }
}

// Eq[h][f][e] = sum_d emb[f,d] Wq[h,d,e];  EkT[h][e][f] likewise for Wk (transposed store)
__global__ void k_proj(const float* __restrict__ emb,
                       const float* __restrict__ Wq, const float* __restrict__ Wk,
                       float* __restrict__ Eq, float* __restrict__ EkT) {
    int h = blockIdx.y;
    int f = blockIdx.x * 4 + (threadIdx.x >> 6);
    int e = threadIdx.x & 63;
    const float* er = emb + f * Dn;
    const float* wq = Wq + h * Dn * En + e;
    const float* wk = Wk + h * Dn * En + e;
    float aq = 0.f, ak = 0.f;
#pragma unroll 4
    for (int d = 0; d < Dn; d++) {
        float ev = er[d];
        aq = fmaf(ev, wq[d * En], aq);
        ak = fmaf(ev, wk[d * En], ak);
    }
    Eq[(h * Fn + f) * En + e] = aq;
    EkT[(h * En + e) * Fn + f] = ak;
}

// Evo[h][g] = sum_d emb[g,d] * wvo[h,d]; one wave per (h,g)
__global__ void k_evo(const float* __restrict__ emb, const float* __restrict__ wvo,
                      float* __restrict__ Evo) {
    int gidx = blockIdx.x * 4 + (threadIdx.x >> 6); // h*Fn+g
    int h = gidx >> 10, g = gidx & 1023;
    int lane = threadIdx.x & 63;
    const float* er = emb + g * Dn + lane;
    const float* wv = wvo + h * Dn + lane;
    float s = 0.f;
#pragma unroll
    for (int d = 0; d < Dn; d += 64) s = fmaf(er[d], wv[d], s);
    s = wsum(s);
    if (lane == 0) Evo[gidx] = s;
}

// S0[h][f][g] = (1/8) sum_e Eq[h][f][e] * EkT[h][e][g]
__global__ void k_s0(const float* __restrict__ Eq, const float* __restrict__ EkT,
                     float* __restrict__ S0) {
    int h = blockIdx.z;
    int f0 = blockIdx.y * 16;
    int g = blockIdx.x * 256 + threadIdx.x;
    const float* ekt = EkT + h * En * Fn + g;
    const float* eq = Eq + (h * Fn + f0) * En;
    float acc[16] = {};
    for (int e = 0; e < En; e++) {
        float kv = ekt[e * Fn];
#pragma unroll
        for (int ff = 0; ff < 16; ff++)
            acc[ff] = fmaf(eq[ff * En + e], kv, acc[ff]);
    }
    float* so = S0 + (h * Fn + f0) * Fn + g;
#pragma unroll
    for (int ff = 0; ff < 16; ff++) so[ff * Fn] = acc[ff] * 0.125f;
}

// per (h,f) row: loop b in tiles of BT, softmax (no max-sub; |t|<~0.06) over g
// of hf*hg*S0, weighted sum of hg*Evo.  8 batches in flight for ILP.
__global__ void k_attn(const float* __restrict__ S0, const float* __restrict__ hbuf,
                       const float* __restrict__ Evo, float* __restrict__ part) {
    __shared__ float hg[BT][Fn];   // 32 KB
    int h = blockIdx.y;
    int wid = threadIdx.x >> 6, lane = threadIdx.x & 63;
    int f = blockIdx.x * 4 + wid;
    const float4* s0row = (const float4*)(S0 + (h * Fn + f) * Fn);
    const float4* evo4 = (const float4*)(Evo + h * Fn);
    float4 s0r[4], evr[4];
#pragma unroll
    for (int k = 0; k < 4; k++) {
        s0r[k] = s0row[k * 64 + lane];
        evr[k] = evo4[k * 64 + lane];
    }
    for (int b0 = 0; b0 < Bn; b0 += BT) {
        __syncthreads();
#pragma unroll
        for (int i = 0; i < BT; i++)
            ((float4*)hg[i])[threadIdx.x] = ((const float4*)(hbuf + (b0 + i) * Fn))[threadIdx.x];
        __syncthreads();
        float s[BT], o[BT], hf[BT];
#pragma unroll
        for (int b = 0; b < BT; b++) { hf[b] = hg[b][f]; s[b] = 0.f; o[b] = 0.f; }
#pragma unroll
        for (int k = 0; k < 4; k++) {
            float4 sv = s0r[k], ev = evr[k];
#pragma unroll
            for (int b = 0; b < BT; b++) {
                float4 hv = ((float4*)hg[b])[k * 64 + lane];
                float p0 = __expf(hf[b] * hv.x * sv.x);
                float p1 = __expf(hf[b] * hv.y * sv.y);
                float p2 = __expf(hf[b] * hv.z * sv.z);
                float p3 = __expf(hf[b] * hv.w * sv.w);
                s[b] += (p0 + p1) + (p2 + p3);
                float o0 = fmaf(p0, hv.x * ev.x, p1 * (hv.y * ev.y));
                float o1 = fmaf(p2, hv.z * ev.z, p3 * (hv.w * ev.w));
                o[b] += o0 + o1;
            }
        }
#pragma unroll
        for (int b = 0; b < BT; b++) { s[b] = wsum(s[b]); o[b] = wsum(o[b]); }
        if (lane == 0) {
#pragma unroll
            for (int b = 0; b < BT; b++)
                part[(h * Bn + b0 + b) * Fn + f] = o[b] / s[b];
        }
    }
}

// xmid = x + bo + sum_h part; LN2 -> h2T[f*B+b]
__global__ void k_mid(const float* __restrict__ x, const float* __restrict__ part,
                      const float* __restrict__ bo, const float* __restrict__ g2,
                      const float* __restrict__ b2, float* __restrict__ xmid,
                      float* __restrict__ h2T) {
    int b = blockIdx.x;
    int tid = threadIdx.x;
    float bov = bo[0];
    float v[4];
    float s = 0.f;
#pragma unroll
    for (int i = 0; i < 4; i++) {
        int f = tid + 256 * i;
        float xv = x[b * Fn + f] + bov;
#pragma unroll
        for (int h = 0; h < Hn; h++) xv += part[(h * Bn + b) * Fn + f];
        v[i] = xv;
        s += xv;
        xmid[b * Fn + f] = xv;
    }
    __shared__ float red[4];
    s = wsum(s);
    int wid = tid >> 6, lane = tid & 63;
    if (lane == 0) red[wid] = s;
    __syncthreads();
    float mu = (red[0] + red[1] + red[2] + red[3]) * (1.f / Fn);
    float vs = 0.f;
#pragma unroll
    for (int i = 0; i < 4; i++) { float d = v[i] - mu; vs = fmaf(d, d, vs); }
    vs = wsum(vs);
    __syncthreads();
    if (lane == 0) red[wid] = vs;
    __syncthreads();
    float var = (red[0] + red[1] + red[2] + red[3]) * (1.f / Fn);
    float rs = rsqrtf(var + LN_EPS);
#pragma unroll
    for (int i = 0; i < 4; i++) {
        int f = tid + 256 * i;
        h2T[f * Bn + b] = (v[i] - mu) * rs * g2[f] + b2[f];
    }
}

// C1p[fc][b][j] = sum_{f in chunk} h2T[f][b] * W1[f][j]
__global__ void k_ffn1(const float* __restrict__ h2T, const float* __restrict__ W1,
                       float* __restrict__ C1p) {
    int j = blockIdx.x * 256 + threadIdx.x;
    int fc = blockIdx.y;
    const float* w = W1 + (fc * FCH1) * FFn + j;
    const float* ht = h2T + (fc * FCH1) * Bn;
    float acc[Bn] = {};
    for (int f = 0; f < FCH1; f++) {
        float wv = w[f * FFn];
#pragma unroll
        for (int b = 0; b < Bn; b++) acc[b] = fmaf(ht[f * Bn + b], wv, acc[b]);
    }
    float* cp = C1p + (fc * Bn) * FFn + j;
#pragma unroll
    for (int b = 0; b < Bn; b++) cp[b * FFn] = acc[b];
}

// U^T[j][b] = gelu(bf1[j] + sum_fc C1p[fc][b][j])
__global__ void k_gelu(const float* __restrict__ C1p, const float* __restrict__ bf1,
                       float* __restrict__ UT) {
    int idx = blockIdx.x * 256 + threadIdx.x;  // b*FFn + j
    int b = idx >> 12, j = idx & 4095;
    float s = bf1[j];
#pragma unroll
    for (int fc = 0; fc < FC1; fc++) s += C1p[(fc * Bn + b) * FFn + j];
    float u = 0.5f * s * (1.f + erff(s * 0.70710678118654752f));
    UT[j * Bn + b] = u;
}

// C2p[jc][b][i] = sum_{j in chunk} UT[j][b] * W2[j][i]
__global__ void k_ffn2(const float* __restrict__ UT, const float* __restrict__ W2,
                       float* __restrict__ C2p) {
    int i = blockIdx.x * 256 + threadIdx.x;
    int jc = blockIdx.y;
    const float* w = W2 + (jc * JCH2) * Fn + i;
    const float* ut = UT + (jc * JCH2) * Bn;
    float acc[Bn] = {};
    for (int j = 0; j < JCH2; j++) {
        float wv = w[j * Fn];
#pragma unroll
        for (int b = 0; b < Bn; b++) acc[b] = fmaf(ut[j * Bn + b], wv, acc[b]);
    }
    float* cp = C2p + (jc * Bn) * Fn + i;
#pragma unroll
    for (int b = 0; b < Bn; b++) cp[b * Fn] = acc[b];
}

// out = xmid + bf2 + sum_jc C2p
__global__ void k_final(const float* __restrict__ xmid, const float* __restrict__ C2p,
                        const float* __restrict__ bf2, float* __restrict__ out) {
    int idx = blockIdx.x * 256 + threadIdx.x;  // b*Fn + f
    int b = idx >> 10, f = idx & 1023;
    float s = xmid[idx] + bf2[f];
#pragma unroll
    for (int jc = 0; jc < JC2; jc++) s += C2p[(jc * Bn + b) * Fn + f];
    out[idx] = s;
}

extern "C" void kernel_launch(void* const* d_in, const int* in_sizes, int n_in,
                              void* d_out, int out_size, void* d_ws, size_t ws_size,
                              hipStream_t stream) {
    (void)in_sizes; (void)n_in; (void)out_size; (void)ws_size;
    const float* x   = (const float*)d_in[0];
    const float* emb = (const float*)d_in[1];
    const float* Wq  = (const float*)d_in[2];
    const float* Wk  = (const float*)d_in[3];
    const float* Wv  = (const float*)d_in[4];
    const float* Wo  = (const float*)d_in[5];
    const float* bo  = (const float*)d_in[6];
    const float* g1  = (const float*)d_in[7];
    const float* b1  = (const float*)d_in[8];
    const float* g2  = (const float*)d_in[9];
    const float* b2  = (const float*)d_in[10];
    const float* W1  = (const float*)d_in[11];
    const float* bf1 = (const float*)d_in[12];
    const float* W2  = (const float*)d_in[13];
    const float* bf2 = (const float*)d_in[14];
    float* out = (float*)d_out;

    float* ws = (float*)d_ws;
    size_t o = 0;
    float* S0   = ws + o; o += (size_t)Hn * Fn * Fn;   // 4194304
    float* Eq   = ws + o; o += (size_t)Hn * Fn * En;   // 262144
    float* EkT  = ws + o; o += (size_t)Hn * En * Fn;   // 262144
    float* Evo  = ws + o; o += (size_t)Hn * Fn;        // 4096
    float* wvo  = ws + o; o += (size_t)Hn * Dn;        // 1024
    float* hbuf = ws + o; o += (size_t)Bn * Fn;        // 32768
    float* part = ws + o; o += (size_t)Hn * Bn * Fn;   // 131072
    float* xmid = ws + o; o += (size_t)Bn * Fn;        // 32768
    float* h2T  = ws + o; o += (size_t)Fn * Bn;        // 32768
    float* C1p  = ws + o; o += (size_t)FC1 * Bn * FFn; // 2097152
    float* UT   = ws + o; o += (size_t)FFn * Bn;       // 131072
    float* C2p  = ws + o; o += (size_t)JC2 * Bn * Fn;  // 1048576

    k_wvo<<<dim3(Hn * Dn / 256), 256, 0, stream>>>(Wv, Wo, wvo);
    k_ln1<<<dim3(Bn), 256, 0, stream>>>(x, g1, b1, hbuf);
    k_proj<<<dim3(Fn / 4, Hn), 256, 0, stream>>>(emb, Wq, Wk, Eq, EkT);
    k_evo<<<dim3(Hn * Fn / 4), 256, 0, stream>>>(emb, wvo, Evo);
    k_s0<<<dim3(Fn / 256, Fn / 16, Hn), 256, 0, stream>>>(Eq, EkT, S0);
    k_attn<<<dim3(Fn / 4, Hn), 256, 0, stream>>>(S0, hbuf, Evo, part);
    k_mid<<<dim3(Bn), 256, 0, stream>>>(x, part, bo, g2, b2, xmid, h2T);
    k_ffn1<<<dim3(FFn / 256, FC1), 256, 0, stream>>>(h2T, W1, C1p);
    k_gelu<<<dim3(Bn * FFn / 256), 256, 0, stream>>>(C1p, bf1, UT);
    k_ffn2<<<dim3(Fn / 256, JC2), 256, 0, stream>>>(UT, W2, C2p);
    k_final<<<dim3(Bn * Fn / 256), 256, 0, stream>>>(xmid, C2p, bf2, out);
}